// Round 1
// baseline (1636.867 us; speedup 1.0000x reference)
//
#include <hip/hip_runtime.h>
#include <math.h>

#define DEV __device__ __forceinline__

DEV float gelu_f(float v) { return 0.5f * v * (1.0f + erff(v * 0.70710678118654752f)); }
DEV float softplus_f(float v) { return v > 15.0f ? v : log1pf(expf(v)); }

DEV unsigned short f2bf(float v) {
    unsigned int u = __float_as_uint(v);
    unsigned int r = (u + 0x7fffu + ((u >> 16) & 1u)) >> 16;
    return (unsigned short)r;
}
DEV float bf2f(unsigned short h) { return __uint_as_float(((unsigned int)h) << 16); }

// ---------------- ws layout (float offsets) ----------------
// A-matrices of the 4 MLPs (each up to 129 x 8)
#define WS_A(j)     ((j) * 1040)
#define WS_KH(c)    (4160 + (c) * 256)              // 128 x 256 circulant kernels, H branch
#define WS_KW(c)    (4160 + 32768 + (c) * 256)      // 128 x 256, W branch
#define WS_P        (4160 + 65536)                  // 4x256 channel sums
#define WS_S        (WS_P + 1024)                   // 4x256 sigmoid scales
#define WS_YBF_BYTE (286976u)                       // (= (WS_S+1024)*4) y in bf16: 4*256*256*256

struct MlpW { const float *w1, *b1, *w2, *b2, *w3, *b3; };

// ---------------- 1. tiny MLPs: A/B factor matrices ----------------
__global__ void mlp_kernel(MlpW a0, MlpW a1, MlpW a2, MlpW a3, float* ws) {
    int j = blockIdx.x;
    MlpW m = (j == 0) ? a0 : (j == 1) ? a1 : (j == 2) ? a2 : a3;
    int n = (j == 1 || j == 3) ? 128 : 129;
    int i = threadIdx.x;
    if (i >= n) return;
    float g;
    if (j == 1 || j == 3) g = -1.0f + 2.0f * i / 127.0f;      // lam = linspace(-1,1,128)
    else                  g = 2.0f * i / 256.0f - 1.0f;        // omega = 2k/N - 1
    float h1[64], h2[64];
    for (int k = 0; k < 64; k++) h1[k] = gelu_f(g * m.w1[k] + m.b1[k]);
    for (int q = 0; q < 64; q++) {
        float acc = m.b2[q];
        for (int k = 0; k < 64; k++) acc += h1[k] * m.w2[q * 64 + k];
        h2[q] = gelu_f(acc);
    }
    float* outp = ws + WS_A(j) + i * 8;
    for (int r = 0; r < 8; r++) {
        float acc = m.b3[r];
        for (int k = 0; k < 64; k++) acc += h2[k] * m.w3[r * 64 + k];
        outp[r] = acc;
    }
}

// ---------------- 2. gates -> circulant kernels k_c[n] ----------------
__global__ void gatek_kernel(float* ws) {
    int br = blockIdx.x >> 7, c = blockIdx.x & 127;
    const float* A = ws + WS_A(br == 0 ? 0 : 2);   // omega MLP out (129 x 8)
    const float* B = ws + WS_A(br == 0 ? 1 : 3);   // lam   MLP out (128 x 8)
    __shared__ float G[129];
    int t = threadIdx.x;
    if (t < 129) {
        float acc = 0.f;
        for (int r = 0; r < 8; r++) acc += A[t * 8 + r] * B[c * 8 + r];
        G[t] = softplus_f(acc) * 0.35355339059327373f;   // / sqrt(8)
    }
    __syncthreads();
    float g0 = G[0], g128 = G[128];
    float acc = g0 + ((t & 1) ? -g128 : g128);
    for (int f = 1; f < 128; f++) {
        int idx = (f * t) & 255;
        acc += 2.0f * G[f] * cosf(idx * 0.02454369260617026f);  // 2*pi/256
    }
    float* kout = ws + (br == 0 ? WS_KH(c) : WS_KW(c));
    kout[t] = acc * (1.0f / 256.0f);
}

// ---------------- 3. gating GEMMs (both branches) ----------------
// HC (br=0):  Y[b,c]      = M_c @ X[b,c]        (A circulant, B = x rows)
// WC (br=1):  Y[b,128+c]  = X[b,128+c] @ Mw_c   (A = x rows, B circulant; Mw symmetric)
__global__ __launch_bounds__(256) void gate_gemm(const float* __restrict__ x, float* ws) {
    const int tile = blockIdx.x;            // 0..3 : mt = tile>>1, nt = tile&1
    const int c    = blockIdx.y;            // 0..127
    const int zb   = blockIdx.z;            // 0..7
    const int b = zb >> 1, br = zb & 1;
    const int m0 = (tile >> 1) * 128, n0 = (tile & 1) * 128;
    const int t = threadIdx.x;
    const int tx = t & 15, ty = t >> 4;

    const float* kbuf = ws + (br == 0 ? WS_KH(c) : WS_KW(c));
    const int ch = (br == 0) ? c : 128 + c;
    const float* xmat = x + ((size_t)(b * 256 + ch)) * 65536u;

    __shared__ float As[16][132];
    __shared__ float Bs[16][132];

    float acc[8][8];
#pragma unroll
    for (int i = 0; i < 8; i++)
#pragma unroll
        for (int j = 0; j < 8; j++) acc[i][j] = 0.f;

    for (int k0 = 0; k0 < 256; k0 += 16) {
#pragma unroll
        for (int i = 0; i < 8; i++) {       // stage A (128 x 16)
            int e = t + 256 * i;
            int kk = e & 15, m = e >> 4;
            float v;
            if (br == 0) v = kbuf[(m0 + m - k0 - kk) & 255];
            else         v = xmat[(size_t)(m0 + m) * 256 + k0 + kk];
            As[kk][m] = v;
        }
#pragma unroll
        for (int i = 0; i < 8; i++) {       // stage B (16 x 128)
            int e = t + 256 * i;
            int n = e & 127, kk = e >> 7;
            float v;
            if (br == 0) v = xmat[(size_t)(k0 + kk) * 256 + n0 + n];
            else         v = kbuf[(k0 + kk - n0 - n) & 255];
            Bs[kk][n] = v;
        }
        __syncthreads();
#pragma unroll
        for (int kk = 0; kk < 16; kk++) {
            float a[8], bb[8];
            *(float4*)&a[0]  = *(const float4*)&As[kk][ty * 4];
            *(float4*)&a[4]  = *(const float4*)&As[kk][64 + ty * 4];
            *(float4*)&bb[0] = *(const float4*)&Bs[kk][tx * 4];
            *(float4*)&bb[4] = *(const float4*)&Bs[kk][64 + tx * 4];
#pragma unroll
            for (int i = 0; i < 8; i++)
#pragma unroll
                for (int j = 0; j < 8; j++) acc[i][j] += a[i] * bb[j];
        }
        __syncthreads();
    }

    // epilogue: bf16 y + per-(b,ch) sum for attention mean
    unsigned short* ybf = (unsigned short*)((char*)ws + WS_YBF_BYTE);
    size_t ybase = ((size_t)(b * 256 + ch)) * 65536u;
    float lsum = 0.f;
#pragma unroll
    for (int ih = 0; ih < 2; ih++)
#pragma unroll
        for (int i = 0; i < 4; i++) {
            int m = m0 + ih * 64 + ty * 4 + i;
#pragma unroll
            for (int jh = 0; jh < 2; jh++) {
                ushort4 pack;
#pragma unroll
                for (int j = 0; j < 4; j++) {
                    float v = acc[ih * 4 + i][jh * 4 + j];
                    lsum += v;
                    ((unsigned short*)&pack)[j] = f2bf(v);
                }
                *(ushort4*)&ybf[ybase + (size_t)m * 256 + n0 + jh * 64 + tx * 4] = pack;
            }
        }
    for (int off = 32; off; off >>= 1) lsum += __shfl_down(lsum, off, 64);
    __shared__ float wsum[4];
    if ((t & 63) == 0) wsum[t >> 6] = lsum;
    __syncthreads();
    if (t == 0) atomicAdd(ws + WS_P + b * 256 + ch, wsum[0] + wsum[1] + wsum[2] + wsum[3]);
}

// ---------------- 4. channel attention scales ----------------
__global__ void attn_kernel(const float* __restrict__ ca_w1, const float* __restrict__ ca_b1,
                            const float* __restrict__ ca_dw, const float* __restrict__ ca_db,
                            float* ws) {
    int b = blockIdx.x, o = threadIdx.x;
    __shared__ float pm[256];
    pm[o] = ws[WS_P + b * 256 + o] * (1.0f / 65536.0f);
    __syncthreads();
    float acc = ca_b1[o];
    for (int c2 = 0; c2 < 256; c2++) acc += ca_w1[o * 256 + c2] * pm[c2];
    float q = gelu_f(acc);
    float tv = q * ca_dw[o * 9 + 4] + ca_db[o];          // depthwise 3x3 center tap
    ws[WS_S + b * 256 + o] = 1.0f / (1.0f + expf(-tv));
}

// ---------------- 5. 1x1 conv + BN + GELU + residual ----------------
__global__ __launch_bounds__(256) void conv_gemm(
    const float* __restrict__ x, const float* __restrict__ lc_w,
    const float* __restrict__ bn_g, const float* __restrict__ bn_b,
    const float* __restrict__ bn_m, const float* __restrict__ bn_v,
    float* __restrict__ out, float* ws) {
    const int mt = blockIdx.x;          // 0..1 (fastest -> B-tile L2 reuse across o-tiles)
    const int nt = blockIdx.y;          // 0..511
    const int b  = blockIdx.z;
    const int m0 = mt * 128, n0 = nt * 128;
    const int t = threadIdx.x, tx = t & 15, ty = t >> 4;
    const unsigned short* ybf = (const unsigned short*)((const char*)ws + WS_YBF_BYTE);
    const float* sv = ws + WS_S + b * 256;

    __shared__ float As[16][132];
    __shared__ float Bs[16][132];

    float acc[8][8];
#pragma unroll
    for (int i = 0; i < 8; i++)
#pragma unroll
        for (int j = 0; j < 8; j++) acc[i][j] = 0.f;

    for (int k0 = 0; k0 < 256; k0 += 16) {
#pragma unroll
        for (int i = 0; i < 8; i++) {   // A = lc_w * s  (128 x 16)
            int e = t + 256 * i;
            int kk = e & 15, m = e >> 4;
            As[kk][m] = lc_w[(size_t)(m0 + m) * 256 + k0 + kk] * sv[k0 + kk];
        }
#pragma unroll
        for (int i = 0; i < 8; i++) {   // B = y bf16 (16 x 128)
            int e = t + 256 * i;
            int n = e & 127, kk = e >> 7;
            Bs[kk][n] = bf2f(ybf[((size_t)(b * 256 + k0 + kk)) * 65536u + n0 + n]);
        }
        __syncthreads();
#pragma unroll
        for (int kk = 0; kk < 16; kk++) {
            float a[8], bb[8];
            *(float4*)&a[0]  = *(const float4*)&As[kk][ty * 4];
            *(float4*)&a[4]  = *(const float4*)&As[kk][64 + ty * 4];
            *(float4*)&bb[0] = *(const float4*)&Bs[kk][tx * 4];
            *(float4*)&bb[4] = *(const float4*)&Bs[kk][64 + tx * 4];
#pragma unroll
            for (int i = 0; i < 8; i++)
#pragma unroll
                for (int j = 0; j < 8; j++) acc[i][j] += a[i] * bb[j];
        }
        __syncthreads();
    }

    // epilogue: BN (eval) + GELU + residual
#pragma unroll
    for (int ih = 0; ih < 2; ih++)
#pragma unroll
        for (int i = 0; i < 4; i++) {
            int o = m0 + ih * 64 + ty * 4 + i;
            float inv  = bn_g[o] * rsqrtf(bn_v[o] + 1e-5f);
            float beta = bn_b[o] - bn_m[o] * inv;
            size_t rowbase = ((size_t)(b * 256 + o)) * 65536u;
#pragma unroll
            for (int jh = 0; jh < 2; jh++) {
                int n = n0 + jh * 64 + tx * 4;
                float4 xv = *(const float4*)&x[rowbase + n];
                float4 ov;
                ov.x = xv.x + gelu_f(acc[ih * 4 + i][jh * 4 + 0] * inv + beta);
                ov.y = xv.y + gelu_f(acc[ih * 4 + i][jh * 4 + 1] * inv + beta);
                ov.z = xv.z + gelu_f(acc[ih * 4 + i][jh * 4 + 2] * inv + beta);
                ov.w = xv.w + gelu_f(acc[ih * 4 + i][jh * 4 + 3] * inv + beta);
                *(float4*)&out[rowbase + n] = ov;
            }
        }
}

extern "C" void kernel_launch(void* const* d_in, const int* in_sizes, int n_in,
                              void* d_out, int out_size, void* d_ws, size_t ws_size,
                              hipStream_t stream) {
    const float* x = (const float*)d_in[0];
    MlpW m[4];
    for (int j = 0; j < 4; j++) {
        m[j].w1 = (const float*)d_in[1 + 6 * j + 0];
        m[j].b1 = (const float*)d_in[1 + 6 * j + 1];
        m[j].w2 = (const float*)d_in[1 + 6 * j + 2];
        m[j].b2 = (const float*)d_in[1 + 6 * j + 3];
        m[j].w3 = (const float*)d_in[1 + 6 * j + 4];
        m[j].b3 = (const float*)d_in[1 + 6 * j + 5];
    }
    const float* ca_w1 = (const float*)d_in[25];
    const float* ca_b1 = (const float*)d_in[26];
    const float* ca_dw = (const float*)d_in[27];
    const float* ca_db = (const float*)d_in[28];
    const float* lc_w  = (const float*)d_in[29];
    const float* bn_g  = (const float*)d_in[30];
    const float* bn_b  = (const float*)d_in[31];
    const float* bn_m  = (const float*)d_in[32];
    const float* bn_v  = (const float*)d_in[33];
    float* ws  = (float*)d_ws;
    float* out = (float*)d_out;

    hipLaunchKernelGGL(mlp_kernel, dim3(4), dim3(256), 0, stream, m[0], m[1], m[2], m[3], ws);
    hipLaunchKernelGGL(gatek_kernel, dim3(256), dim3(256), 0, stream, ws);
    hipMemsetAsync(ws + WS_P, 0, 1024 * sizeof(float), stream);
    hipLaunchKernelGGL(gate_gemm, dim3(4, 128, 8), dim3(256), 0, stream, x, ws);
    hipLaunchKernelGGL(attn_kernel, dim3(4), dim3(256), 0, stream, ca_w1, ca_b1, ca_dw, ca_db, ws);
    hipLaunchKernelGGL(conv_gemm, dim3(2, 512, 4), dim3(256), 0, stream,
                       x, lc_w, bn_g, bn_b, bn_m, bn_v, out, ws);
}

// Round 2
// 1091.811 us; speedup vs baseline: 1.4992x; 1.4992x over previous
//
#include <hip/hip_runtime.h>
#include <math.h>

#define DEV __device__ __forceinline__

typedef __attribute__((ext_vector_type(8))) short short8;
typedef __attribute__((ext_vector_type(4))) float floatx4;
typedef unsigned int u32;
typedef unsigned short u16;

DEV float gelu_f(float v) { return 0.5f * v * (1.0f + erff(v * 0.70710678118654752f)); }
DEV float softplus_f(float v) { return v > 15.0f ? v : log1pf(expf(v)); }

DEV u16 f2bf(float v) {
    u32 u = __float_as_uint(v);
    return (u16)((u + 0x7fffu + ((u >> 16) & 1u)) >> 16);
}

DEV void gload_lds16(const void* g, void* l) {
    __builtin_amdgcn_global_load_lds((const __attribute__((address_space(1))) u32*)g,
                                     (__attribute__((address_space(3))) u32*)l, 16, 0, 0);
}

// ---------------- ws layout ----------------
// float offsets
#define WS_A(j)     ((j) * 1040)
#define WS_KBUF     4160                      // 256 x 256 fp32 circulant kernels
#define WS_P        (4160 + 65536)            // 4x256 channel sums
#define WS_S        (WS_P + 1024)             // 4x256 sigmoid scales
// byte offsets
#define Y0_B        286976u                   // y bf16 [b][c][h][w], 134217728 B
#define AW0_B       134504704u                // A_w bf16 [b][o][c],  524288 B
#define CIRC0_B     135028992u                // circulants bf16 [256][256][256], 33554432 B
#define XB0_B       168583424u                // x bf16 (ch<128 transposed), 134217728 B
#define YT0_B       135028992u                // y^T bf16 [b][p][c] — aliases circ+xb (dead after gate)

struct MlpW { const float *w1, *b1, *w2, *b2, *w3, *b3; };

// ---------------- 1. tiny MLPs ----------------
__global__ void mlp_kernel(MlpW a0, MlpW a1, MlpW a2, MlpW a3, float* ws) {
    int j = blockIdx.x;
    MlpW m = (j == 0) ? a0 : (j == 1) ? a1 : (j == 2) ? a2 : a3;
    int n = (j == 1 || j == 3) ? 128 : 129;
    int i = threadIdx.x;
    if (i >= n) return;
    float g;
    if (j == 1 || j == 3) g = -1.0f + 2.0f * i / 127.0f;
    else                  g = 2.0f * i / 256.0f - 1.0f;
    float h1[64], h2[64];
    for (int k = 0; k < 64; k++) h1[k] = gelu_f(g * m.w1[k] + m.b1[k]);
    for (int q = 0; q < 64; q++) {
        float acc = m.b2[q];
        for (int k = 0; k < 64; k++) acc += h1[k] * m.w2[q * 64 + k];
        h2[q] = gelu_f(acc);
    }
    float* outp = ws + WS_A(j) + i * 8;
    for (int r = 0; r < 8; r++) {
        float acc = m.b3[r];
        for (int k = 0; k < 64; k++) acc += h2[k] * m.w3[r * 64 + k];
        outp[r] = acc;
    }
}

// ---------------- 2. gates -> circulant kernel vectors (fp32) ----------------
__global__ void gatek_kernel(float* ws) {
    int br = blockIdx.x >> 7, c = blockIdx.x & 127;
    const float* A = ws + WS_A(br == 0 ? 0 : 2);
    const float* B = ws + WS_A(br == 0 ? 1 : 3);
    __shared__ float G[129];
    int t = threadIdx.x;
    if (t < 129) {
        float acc = 0.f;
        for (int r = 0; r < 8; r++) acc += A[t * 8 + r] * B[c * 8 + r];
        G[t] = softplus_f(acc) * 0.35355339059327373f;
    }
    __syncthreads();
    float g0 = G[0], g128 = G[128];
    float acc = g0 + ((t & 1) ? -g128 : g128);
    for (int f = 1; f < 128; f++) {
        int idx = (f * t) & 255;
        acc += 2.0f * G[f] * cosf(idx * 0.02454369260617026f);
    }
    ws[WS_KBUF + blockIdx.x * 256 + t] = acc * (1.0f / 256.0f);
}

// ---------------- 3. materialize circulant matrices (bf16) ----------------
__global__ void circmat(const float* __restrict__ ws, u16* __restrict__ circ) {
    int mi = blockIdx.x, t = threadIdx.x;
    __shared__ float kl[256];
    kl[t] = ws[WS_KBUF + mi * 256 + t];
    __syncthreads();
    u16* M = circ + (size_t)mi * 65536u;
    for (int it = 0; it < 32; it++) {
        int e = it * 2048 + t * 8;
        int i = e >> 8, j = e & 255;
        u16 tmp[8];
#pragma unroll
        for (int jj = 0; jj < 8; jj++) tmp[jj] = f2bf(kl[(i - j - jj) & 255]);
        *(uint4*)&M[e] = *(uint4*)tmp;
    }
}

// ---------------- 4. prep: x fp32 -> bf16 (ch<128 transposed [w][h]) ----------------
__global__ void prep(const float* __restrict__ x, u16* __restrict__ xb) {
    int tile = blockIdx.x;          // 0..15
    int mat = blockIdx.y;           // 0..1023
    int t = threadIdx.x;
    const float* xm = x + (size_t)mat * 65536u;
    u16* xo = xb + (size_t)mat * 65536u;
    __shared__ float lt[64][65];
    if ((mat & 255) >= 128) {       // WC half: straight cast
        int base = tile * 4096 + t * 16;
#pragma unroll
        for (int q = 0; q < 4; q++) {
            float4 v = *(const float4*)&xm[base + q * 4];
            ushort4 o; o.x = f2bf(v.x); o.y = f2bf(v.y); o.z = f2bf(v.z); o.w = f2bf(v.w);
            *(ushort4*)&xo[base + q * 4] = o;
        }
    } else {                        // HC half: 64x64 tiled transpose
        int w0 = (tile & 3) * 64, h0 = (tile >> 2) * 64;
        int rh = t >> 2, cc = (t & 3) * 16;
#pragma unroll
        for (int q = 0; q < 4; q++) {
            float4 v = *(const float4*)&xm[(h0 + rh) * 256 + w0 + cc + q * 4];
            lt[rh][cc + q * 4 + 0] = v.x; lt[rh][cc + q * 4 + 1] = v.y;
            lt[rh][cc + q * 4 + 2] = v.z; lt[rh][cc + q * 4 + 3] = v.w;
        }
        __syncthreads();
        u16 tmp[16];
#pragma unroll
        for (int j = 0; j < 16; j++) tmp[j] = f2bf(lt[cc + j][rh]);
#pragma unroll
        for (int q = 0; q < 4; q++)
            *(ushort4*)&xo[(w0 + rh) * 256 + h0 + cc + q * 4] = *(ushort4*)&tmp[q * 4];
    }
}

// ---------------- 5. gating GEMMs (bf16 MFMA) ----------------
// HC (br=0): Y = M_c @ X    (A = circulant rows m, B = x^T rows n)
// WC (br=1): Y = X @ M_c    (A = x rows m,         B = circulant rows n)
__global__ __launch_bounds__(256) void gate_gemm(
    const u16* __restrict__ xb, const u16* __restrict__ circ,
    u16* __restrict__ y, float* __restrict__ ws)
{
    const int tile = blockIdx.x, c = blockIdx.y, zb = blockIdx.z;
    const int b = zb >> 1, br = zb & 1;
    const int m0 = (tile >> 1) * 128, n0 = (tile & 1) * 128;
    const int t = threadIdx.x, lane = t & 63, w = t >> 6;
    const int ch = br * 128 + c;

    const u16* Mbase = circ + (size_t)ch * 65536u;
    const u16* Xbase = xb + (size_t)(b * 256 + ch) * 65536u;
    const int rM0 = br ? n0 : m0;
    const int rX0 = br ? m0 : n0;

    __shared__ u16 ldsM[4096];
    __shared__ u16 ldsX[4096];

    const int s1 = t + 256;
    const int kq0 = t >> 7, r0s = t & 127;
    const int kq1 = s1 >> 7, r1s = s1 & 127;
    const u16* gM0 = Mbase + (rM0 + r0s) * 256 + kq0 * 8;
    const u16* gM1 = Mbase + (rM0 + r1s) * 256 + kq1 * 8;
    const u16* gX0 = Xbase + (rX0 + r0s) * 256 + kq0 * 8;
    const u16* gX1 = Xbase + (rX0 + r1s) * 256 + kq1 * 8;
    u16* lM0 = &ldsM[(t & 192) * 8];
    u16* lM1 = &ldsM[((t & 192) + 256) * 8];
    u16* lX0 = &ldsX[(t & 192) * 8];
    u16* lX1 = &ldsX[((t & 192) + 256) * 8];

    floatx4 acc[4][4];
#pragma unroll
    for (int i = 0; i < 4; i++)
#pragma unroll
        for (int j = 0; j < 4; j++) acc[i][j] = (floatx4){0.f, 0.f, 0.f, 0.f};

    const int wm = (w & 1) * 64, wn = (w >> 1) * 64;
    const int fr = lane & 15, fq = lane >> 4;
    const u16* aB = br ? ldsX : ldsM;
    const u16* bB = br ? ldsM : ldsX;

    for (int k0 = 0; k0 < 256; k0 += 32) {
        gload_lds16(gM0, lM0); gload_lds16(gM1, lM1);
        gload_lds16(gX0, lX0); gload_lds16(gX1, lX1);
        gM0 += 32; gM1 += 32; gX0 += 32; gX1 += 32;
        __syncthreads();
        short8 aF[4], bF[4];
#pragma unroll
        for (int i = 0; i < 4; i++) aF[i] = *(const short8*)&aB[(fq * 128 + wm + i * 16 + fr) * 8];
#pragma unroll
        for (int j = 0; j < 4; j++) bF[j] = *(const short8*)&bB[(fq * 128 + wn + j * 16 + fr) * 8];
#pragma unroll
        for (int i = 0; i < 4; i++)
#pragma unroll
            for (int j = 0; j < 4; j++)
                acc[i][j] = __builtin_amdgcn_mfma_f32_16x16x32_bf16(aF[i], bF[j], acc[i][j], 0, 0, 0);
        __syncthreads();
    }

    // epilogue: bf16 y + channel sum
    size_t ybase = (size_t)(b * 256 + ch) * 65536u;
    float lsum = 0.f;
#pragma unroll
    for (int i = 0; i < 4; i++)
#pragma unroll
        for (int r = 0; r < 4; r++) {
            int row = m0 + wm + i * 16 + fq * 4 + r;
            size_t rb = ybase + (size_t)row * 256;
#pragma unroll
            for (int j = 0; j < 4; j++) {
                float v = acc[i][j][r];
                lsum += v;
                y[rb + n0 + wn + j * 16 + fr] = f2bf(v);
            }
        }
    for (int off = 32; off; off >>= 1) lsum += __shfl_down(lsum, off, 64);
    __shared__ float wsum[4];
    if (lane == 0) wsum[w] = lsum;
    __syncthreads();
    if (t == 0) atomicAdd(ws + WS_P + b * 256 + ch, wsum[0] + wsum[1] + wsum[2] + wsum[3]);
}

// ---------------- 6. attention scales + A_w = lc_w * s (bf16) ----------------
__global__ void attn_kernel(const float* __restrict__ ca_w1, const float* __restrict__ ca_b1,
                            const float* __restrict__ ca_dw, const float* __restrict__ ca_db,
                            const float* __restrict__ lc_w, float* ws, u16* __restrict__ aw) {
    int b = blockIdx.x, o = threadIdx.x;
    __shared__ float pm[256];
    __shared__ float sl[256];
    pm[o] = ws[WS_P + b * 256 + o] * (1.0f / 65536.0f);
    __syncthreads();
    float acc = ca_b1[o];
    for (int c2 = 0; c2 < 256; c2++) acc += ca_w1[o * 256 + c2] * pm[c2];
    float q = gelu_f(acc);
    float tv = q * ca_dw[o * 9 + 4] + ca_db[o];
    float s = 1.0f / (1.0f + expf(-tv));
    ws[WS_S + b * 256 + o] = s;
    sl[o] = s;
    __syncthreads();
    u16* awb = aw + b * 65536;
    for (int row = 0; row < 256; row++)
        awb[row * 256 + o] = f2bf(lc_w[row * 256 + o] * sl[o]);
}

// ---------------- 7. y -> y^T (bf16) ----------------
__global__ void ytrans(const u16* __restrict__ y, u16* __restrict__ yt) {
    int pt = blockIdx.x, ct = blockIdx.y, b = blockIdx.z;
    const u16* yb = y + (size_t)b * 16777216u;
    u16* ytb = yt + (size_t)b * 16777216u;
    int p0 = pt * 64, c0 = ct * 64;
    __shared__ u16 lt[64][74];   // 37-dword pitch: conflict-lite
    int t = threadIdx.x;
    int rr = t >> 3, pc = (t & 7) * 8;
#pragma unroll
    for (int it = 0; it < 2; it++) {
        int row = rr + it * 32;
        ushort4 a0 = *(const ushort4*)&yb[(size_t)(c0 + row) * 65536u + p0 + pc];
        ushort4 a1 = *(const ushort4*)&yb[(size_t)(c0 + row) * 65536u + p0 + pc + 4];
        lt[row][pc + 0] = a0.x; lt[row][pc + 1] = a0.y; lt[row][pc + 2] = a0.z; lt[row][pc + 3] = a0.w;
        lt[row][pc + 4] = a1.x; lt[row][pc + 5] = a1.y; lt[row][pc + 6] = a1.z; lt[row][pc + 7] = a1.w;
    }
    __syncthreads();
#pragma unroll
    for (int it = 0; it < 2; it++) {
        int row = rr + it * 32;       // p-rel
        u16 tmp[8];
#pragma unroll
        for (int j = 0; j < 8; j++) tmp[j] = lt[pc + j][row];
        *(uint4*)&ytb[(size_t)(p0 + row) * 256 + c0 + pc] = *(uint4*)tmp;
    }
}

// ---------------- 8. 1x1 conv GEMM + BN + GELU + residual ----------------
__global__ __launch_bounds__(256) void conv_gemm(
    const float* __restrict__ x, const u16* __restrict__ aw, const u16* __restrict__ yt,
    const float* __restrict__ bn_g, const float* __restrict__ bn_b,
    const float* __restrict__ bn_m, const float* __restrict__ bn_v,
    float* __restrict__ out)
{
    const int m0 = blockIdx.x * 128;      // o
    const int n0 = blockIdx.y * 128;      // p
    const int b = blockIdx.z;
    const int t = threadIdx.x, lane = t & 63, w = t >> 6;

    const u16* Abase = aw + (size_t)b * 65536u;
    const u16* Bbase = yt + (size_t)b * 16777216u;

    __shared__ u16 ldsA[4096];
    __shared__ u16 ldsB[4096];

    const int s1 = t + 256;
    const int kq0 = t >> 7, r0s = t & 127;
    const int kq1 = s1 >> 7, r1s = s1 & 127;
    const u16* gA0 = Abase + (m0 + r0s) * 256 + kq0 * 8;
    const u16* gA1 = Abase + (m0 + r1s) * 256 + kq1 * 8;
    const u16* gB0 = Bbase + (size_t)(n0 + r0s) * 256 + kq0 * 8;
    const u16* gB1 = Bbase + (size_t)(n0 + r1s) * 256 + kq1 * 8;
    u16* lA0 = &ldsA[(t & 192) * 8];
    u16* lA1 = &ldsA[((t & 192) + 256) * 8];
    u16* lB0 = &ldsB[(t & 192) * 8];
    u16* lB1 = &ldsB[((t & 192) + 256) * 8];

    floatx4 acc[4][4];
#pragma unroll
    for (int i = 0; i < 4; i++)
#pragma unroll
        for (int j = 0; j < 4; j++) acc[i][j] = (floatx4){0.f, 0.f, 0.f, 0.f};

    const int wm = (w & 1) * 64, wn = (w >> 1) * 64;
    const int fr = lane & 15, fq = lane >> 4;

    for (int k0 = 0; k0 < 256; k0 += 32) {
        gload_lds16(gA0, lA0); gload_lds16(gA1, lA1);
        gload_lds16(gB0, lB0); gload_lds16(gB1, lB1);
        gA0 += 32; gA1 += 32; gB0 += 32; gB1 += 32;
        __syncthreads();
        short8 aF[4], bF[4];
#pragma unroll
        for (int i = 0; i < 4; i++) aF[i] = *(const short8*)&ldsA[(fq * 128 + wm + i * 16 + fr) * 8];
#pragma unroll
        for (int j = 0; j < 4; j++) bF[j] = *(const short8*)&ldsB[(fq * 128 + wn + j * 16 + fr) * 8];
#pragma unroll
        for (int i = 0; i < 4; i++)
#pragma unroll
            for (int j = 0; j < 4; j++)
                acc[i][j] = __builtin_amdgcn_mfma_f32_16x16x32_bf16(aF[i], bF[j], acc[i][j], 0, 0, 0);
        __syncthreads();
    }

#pragma unroll
    for (int i = 0; i < 4; i++)
#pragma unroll
        for (int r = 0; r < 4; r++) {
            int o = m0 + wm + i * 16 + fq * 4 + r;
            float inv = bn_g[o] * rsqrtf(bn_v[o] + 1e-5f);
            float beta = bn_b[o] - bn_m[o] * inv;
            size_t rowb = (size_t)(b * 256 + o) * 65536u;
#pragma unroll
            for (int j = 0; j < 4; j++) {
                int p = n0 + wn + j * 16 + fr;
                float v = acc[i][j][r];
                out[rowb + p] = x[rowb + p] + gelu_f(v * inv + beta);
            }
        }
}

extern "C" void kernel_launch(void* const* d_in, const int* in_sizes, int n_in,
                              void* d_out, int out_size, void* d_ws, size_t ws_size,
                              hipStream_t stream) {
    const float* x = (const float*)d_in[0];
    MlpW m[4];
    for (int j = 0; j < 4; j++) {
        m[j].w1 = (const float*)d_in[1 + 6 * j + 0];
        m[j].b1 = (const float*)d_in[1 + 6 * j + 1];
        m[j].w2 = (const float*)d_in[1 + 6 * j + 2];
        m[j].b2 = (const float*)d_in[1 + 6 * j + 3];
        m[j].w3 = (const float*)d_in[1 + 6 * j + 4];
        m[j].b3 = (const float*)d_in[1 + 6 * j + 5];
    }
    const float* ca_w1 = (const float*)d_in[25];
    const float* ca_b1 = (const float*)d_in[26];
    const float* ca_dw = (const float*)d_in[27];
    const float* ca_db = (const float*)d_in[28];
    const float* lc_w  = (const float*)d_in[29];
    const float* bn_g  = (const float*)d_in[30];
    const float* bn_b  = (const float*)d_in[31];
    const float* bn_m  = (const float*)d_in[32];
    const float* bn_v  = (const float*)d_in[33];

    char* wsb = (char*)d_ws;
    float* ws = (float*)d_ws;
    u16* ybf  = (u16*)(wsb + Y0_B);
    u16* aw   = (u16*)(wsb + AW0_B);
    u16* circ = (u16*)(wsb + CIRC0_B);
    u16* xbb  = (u16*)(wsb + XB0_B);
    u16* yt   = (u16*)(wsb + YT0_B);
    float* out = (float*)d_out;

    hipLaunchKernelGGL(mlp_kernel, dim3(4), dim3(256), 0, stream, m[0], m[1], m[2], m[3], ws);
    hipLaunchKernelGGL(gatek_kernel, dim3(256), dim3(256), 0, stream, ws);
    hipLaunchKernelGGL(circmat, dim3(256), dim3(256), 0, stream, ws, circ);
    hipLaunchKernelGGL(prep, dim3(16, 1024), dim3(256), 0, stream, x, xbb);
    hipMemsetAsync(ws + WS_P, 0, 1024 * sizeof(float), stream);
    hipLaunchKernelGGL(gate_gemm, dim3(4, 128, 8), dim3(256), 0, stream, xbb, circ, ybf, ws);
    hipLaunchKernelGGL(attn_kernel, dim3(4), dim3(256), 0, stream,
                       ca_w1, ca_b1, ca_dw, ca_db, lc_w, ws, aw);
    hipLaunchKernelGGL(ytrans, dim3(1024, 4, 4), dim3(256), 0, stream, ybf, yt);
    hipLaunchKernelGGL(conv_gemm, dim3(2, 512, 4), dim3(256), 0, stream,
                       x, aw, yt, bn_g, bn_b, bn_m, bn_v, out);
}